// Round 9
// baseline (75.417 us; speedup 1.0000x reference)
//
#include <hip/hip_runtime.h>
#include <math.h>

// ---------------------------------------------------------------------------
// PrefrontalCortex, batch=1, fp32 — R9: R8 structure, rebalanced.
//  * All phases 256-thr blocks; bg units redistributed so every phase keeps
//    >=512 blocks issuing loads (R8's K3/K5 had 193 blocks -> CUs idle).
//  * out_rv moved K8 -> K6 (depends only on rv; K6 is a latency burst).
//  * softmax_rw now the R7-verified 256-thread variant; rv-reduce float4.
// bg units: u<8192 -> gh[u]=W_hh[u,:]*h_prev ; u>=8192 -> gx[u-8192]=
// W_ih[u-8192,0:2048]*x. Distribution: K1[0,3584) K2[3584,7680)
// K3[7680,9728) K4[9728,14336) K5[14336,16384).
// ---------------------------------------------------------------------------

#define HIDDEN_DIM 2048
#define MEM_SLOTS 4096
#define MEM_DIM 1024

typedef float floatx4 __attribute__((ext_vector_type(4)));

static __device__ __forceinline__ float sigmoidf_(float x) {
    return 1.0f / (1.0f + expf(-x));
}

// wave-level dot, K4F4 float4 elems (256|512), valid on lane 0.
template<int K4F4>
static __device__ __forceinline__ float rowdot(const float4* __restrict__ Wr,
                                               const float4* __restrict__ v4,
                                               int lane) {
    float a0 = 0.f, a1 = 0.f, a2 = 0.f, a3 = 0.f;
#pragma unroll
    for (int i0 = 0; i0 < K4F4; i0 += 256) {
        int i = i0 + lane;
        floatx4 w0 = *(const floatx4*)(Wr + i);
        floatx4 w1 = *(const floatx4*)(Wr + i + 64);
        floatx4 w2 = *(const floatx4*)(Wr + i + 128);
        floatx4 w3 = *(const floatx4*)(Wr + i + 192);
        floatx4 x0 = *(const floatx4*)(v4 + i);
        floatx4 x1 = *(const floatx4*)(v4 + i + 64);
        floatx4 x2 = *(const floatx4*)(v4 + i + 128);
        floatx4 x3 = *(const floatx4*)(v4 + i + 192);
        a0 = fmaf(w0.x, x0.x, a0); a0 = fmaf(w0.y, x0.y, a0);
        a0 = fmaf(w0.z, x0.z, a0); a0 = fmaf(w0.w, x0.w, a0);
        a1 = fmaf(w1.x, x1.x, a1); a1 = fmaf(w1.y, x1.y, a1);
        a1 = fmaf(w1.z, x1.z, a1); a1 = fmaf(w1.w, x1.w, a1);
        a2 = fmaf(w2.x, x2.x, a2); a2 = fmaf(w2.y, x2.y, a2);
        a2 = fmaf(w2.z, x2.z, a2); a2 = fmaf(w2.w, x2.w, a2);
        a3 = fmaf(w3.x, x3.x, a3); a3 = fmaf(w3.y, x3.y, a3);
        a3 = fmaf(w3.z, x3.z, a3); a3 = fmaf(w3.w, x3.w, a3);
    }
    float acc = (a0 + a1) + (a2 + a3);
#pragma unroll
    for (int off = 32; off > 0; off >>= 1) acc += __shfl_down(acc, off);
    return acc;
}

static __device__ __forceinline__ void do_bg(int u, const float4* whh4,
                                             const float4* wih4, const float4* h4,
                                             const float4* x4, float* gh, float* gx,
                                             int lane) {
    if (u < 8192) {
        float d = rowdot<512>(whh4 + (size_t)u * 512, h4, lane);
        if (lane == 0) gh[u] = d;
    } else {
        int r = u - 8192;
        float d = rowdot<512>(wih4 + (size_t)r * 768, x4, lane);
        if (lane == 0) gx[r] = d;
    }
}

// K1: readkey (blocks 0-255) + bg [0,3584) (blocks 256-1151). grid 1152x256.
__global__ void k1_rk_bg(const float* __restrict__ read_W, const float* __restrict__ read_b,
                         const float* __restrict__ h_prev, const float* __restrict__ W_hh,
                         const float* __restrict__ W_ih, const float* __restrict__ x,
                         float* __restrict__ rk, float* __restrict__ gh, float* __restrict__ gx) {
    int lane = threadIdx.x & 63;
    int wid = threadIdx.x >> 6;
    const float4* h4 = (const float4*)h_prev;
    if (blockIdx.x < 256) {
        int r = blockIdx.x * 4 + wid;
        float d = rowdot<512>((const float4*)read_W + (size_t)r * 512, h4, lane);
        if (lane == 0) rk[r] = tanhf(d + read_b[r]);
    } else {
        int u = (blockIdx.x - 256) * 4 + wid;           // [0,3584)
        do_bg(u, (const float4*)W_hh, (const float4*)W_ih, h4,
              (const float4*)x, gh, gx, lane);
    }
}

// K2: sim (blocks 0-1023) + bg [3584,7680) (blocks 1024-2047). grid 2048x256.
__global__ void k2_sim_bg(const float* __restrict__ memory, const float* __restrict__ rk,
                          const float* __restrict__ h_prev, const float* __restrict__ W_hh,
                          const float* __restrict__ W_ih, const float* __restrict__ x,
                          float* __restrict__ sim, float* __restrict__ gh, float* __restrict__ gx) {
    int lane = threadIdx.x & 63;
    int wid = threadIdx.x >> 6;
    if (blockIdx.x < 1024) {
        int r = blockIdx.x * 4 + wid;
        float d = rowdot<256>((const float4*)memory + (size_t)r * 256, (const float4*)rk, lane);
        if (lane == 0) sim[r] = d;
    } else {
        int u = 3584 + (blockIdx.x - 1024) * 4 + wid;   // [3584,7680)
        do_bg(u, (const float4*)W_hh, (const float4*)W_ih, (const float4*)h_prev,
              (const float4*)x, gh, gx, lane);
    }
}

// K3: softmax_rw (block 0, 256 thr, R7-verified) + bg [7680,9728). grid 513x256.
__global__ void k3_smx_bg(const float* __restrict__ sim, const float* __restrict__ usage,
                          float* __restrict__ rw, float* __restrict__ usage_out,
                          const float* __restrict__ h_prev, const float* __restrict__ W_hh,
                          const float* __restrict__ W_ih, const float* __restrict__ x,
                          float* __restrict__ gh, float* __restrict__ gx) {
    int tid = threadIdx.x;
    int lane = tid & 63, wid = tid >> 6;
    if (blockIdx.x != 0) {
        int u = 7680 + (blockIdx.x - 1) * 4 + wid;      // [7680,9728)
        do_bg(u, (const float4*)W_hh, (const float4*)W_ih, (const float4*)h_prev,
              (const float4*)x, gh, gx, lane);
        return;
    }
    __shared__ float sm[16];
    float v[16];
    float m = -1e30f;
#pragma unroll
    for (int j = 0; j < 16; ++j) { v[j] = sim[tid + 256 * j]; m = fmaxf(m, v[j]); }
#pragma unroll
    for (int off = 32; off > 0; off >>= 1) m = fmaxf(m, __shfl_down(m, off));
    if (lane == 0) sm[wid] = m;
    __syncthreads();
    if (tid == 0) sm[8] = fmaxf(fmaxf(sm[0], sm[1]), fmaxf(sm[2], sm[3]));
    __syncthreads();
    float mm = sm[8];
    float e[16], s = 0.f;
#pragma unroll
    for (int j = 0; j < 16; ++j) { e[j] = expf(v[j] - mm); s += e[j]; }
#pragma unroll
    for (int off = 32; off > 0; off >>= 1) s += __shfl_down(s, off);
    __syncthreads();
    if (lane == 0) sm[wid] = s;
    __syncthreads();
    if (tid == 0) sm[9] = sm[0] + sm[1] + sm[2] + sm[3];
    __syncthreads();
    float inv = 1.f / sm[9];
#pragma unroll
    for (int j = 0; j < 16; ++j) {
        int idx = tid + 256 * j;
        float r = e[j] * inv;
        rw[idx] = r;
        usage_out[idx] = usage[idx] + r;
    }
}

// K4: rv-partial (blocks 0-63) + bg [9728,14336) (blocks 64-1215). grid 1216x256.
__global__ void k4_rvp_bg(const float* __restrict__ memory, const float* __restrict__ rw,
                          float* __restrict__ partial,
                          const float* __restrict__ h_prev, const float* __restrict__ W_hh,
                          const float* __restrict__ W_ih, const float* __restrict__ x,
                          float* __restrict__ gh, float* __restrict__ gx) {
    int t = threadIdx.x;
    int lane = t & 63;
    if (blockIdx.x >= 64) {
        int u = 9728 + (blockIdx.x - 64) * 4 + (t >> 6);  // [9728,14336)
        do_bg(u, (const float4*)W_hh, (const float4*)W_ih, (const float4*)h_prev,
              (const float4*)x, gh, gx, lane);
        return;
    }
    int chunk = blockIdx.x;
    const float4* mem4 = (const float4*)memory;
    float4 acc = make_float4(0.f, 0.f, 0.f, 0.f);
    int s0 = chunk * 64;
    for (int s = s0; s < s0 + 64; ++s) {
        float w = rw[s];
        float4 m = mem4[(size_t)s * 256 + t];
        acc.x = fmaf(w, m.x, acc.x);
        acc.y = fmaf(w, m.y, acc.y);
        acc.z = fmaf(w, m.z, acc.z);
        acc.w = fmaf(w, m.w, acc.w);
    }
    ((float4*)partial)[chunk * 256 + t] = acc;
}

// K5: rv-reduce (block 0, 256 thr, float4) + bg [14336,16384). grid 513x256.
__global__ void k5_rvr_bg(const float* __restrict__ partial, float* __restrict__ rv,
                          const float* __restrict__ h_prev, const float* __restrict__ W_hh,
                          const float* __restrict__ W_ih, const float* __restrict__ x,
                          float* __restrict__ gh, float* __restrict__ gx) {
    int tid = threadIdx.x;
    int lane = tid & 63, wid = tid >> 6;
    if (blockIdx.x != 0) {
        int u = 14336 + (blockIdx.x - 1) * 4 + wid;     // [14336,16384)
        do_bg(u, (const float4*)W_hh, (const float4*)W_ih, (const float4*)h_prev,
              (const float4*)x, gh, gx, lane);
        return;
    }
    const float4* p4 = (const float4*)partial;
    float4 acc = make_float4(0.f, 0.f, 0.f, 0.f);
    for (int k = 0; k < 64; ++k) {
        float4 p = p4[k * 256 + tid];
        acc.x += p.x; acc.y += p.y; acc.z += p.z; acc.w += p.w;
    }
    ((float4*)rv)[tid] = acc;
}

// K6: grv (waves 0-8191) + out_rv (waves 8192-10239). grid 2560x256.
__global__ void k6_grv_outrv(const float* __restrict__ W_ih, const float* __restrict__ out_W,
                             const float* __restrict__ rv, float* __restrict__ grv,
                             float* __restrict__ outrv) {
    int lane = threadIdx.x & 63;
    int gw = blockIdx.x * 4 + (threadIdx.x >> 6);
    const float4* rv4 = (const float4*)rv;
    if (gw < 8192) {
        float d = rowdot<256>((const float4*)W_ih + (size_t)gw * 768 + 512, rv4, lane);
        if (lane == 0) grv[gw] = d;
    } else {
        int o = gw - 8192;
        float d = rowdot<256>((const float4*)out_W + (size_t)o * 768 + 512, rv4, lane);
        if (lane == 0) outrv[o] = d;
    }
}

// K7: LSTM elementwise. grid 8x256.
__global__ void k7_lstm(const float* __restrict__ gx, const float* __restrict__ grv,
                        const float* __restrict__ gh, const float* __restrict__ b_ih,
                        const float* __restrict__ b_hh, const float* __restrict__ c_prev,
                        float* __restrict__ c_new, float* __restrict__ h_new) {
    int t = blockIdx.x * 256 + threadIdx.x;
    float gi = gx[t]        + grv[t]        + gh[t]        + b_ih[t]        + b_hh[t];
    float gf = gx[2048 + t] + grv[2048 + t] + gh[2048 + t] + b_ih[2048 + t] + b_hh[2048 + t];
    float gg = gx[4096 + t] + grv[4096 + t] + gh[4096 + t] + b_ih[4096 + t] + b_hh[4096 + t];
    float go = gx[6144 + t] + grv[6144 + t] + gh[6144 + t] + b_ih[6144 + t] + b_hh[6144 + t];
    float c = sigmoidf_(gf) * c_prev[t] + sigmoidf_(gi) * tanhf(gg);
    float h = sigmoidf_(go) * tanhf(c);
    c_new[t] = c;
    h_new[t] = h;
}

// K8: head rows 1024..7168 (u<6145) + out_h (u<8193). grid 2049x256.
__global__ void k8_head_out(const float* __restrict__ head_W, const float* __restrict__ head_b,
                            const float* __restrict__ out_W, const float* __restrict__ h_new,
                            float* __restrict__ params, float* __restrict__ outh) {
    int lane = threadIdx.x & 63;
    int u = blockIdx.x * 4 + (threadIdx.x >> 6);
    const float4* hn4 = (const float4*)h_new;
    if (u < 6145) {
        int r = 1024 + u;
        float d = rowdot<512>((const float4*)head_W + (size_t)r * 512, hn4, lane);
        if (lane == 0) params[r] = d + head_b[r];
    } else if (u < 8193) {
        int o = u - 6145;
        float d = rowdot<512>((const float4*)out_W + (size_t)o * 768, hn4, lane);
        if (lane == 0) outh[o] = d;
    }
}

// K9: softmax_w. grid 1x1024.
__global__ void k9_smxw(const float* __restrict__ params, float* __restrict__ wv,
                        float* __restrict__ erase, float* __restrict__ addv) {
    __shared__ float sm[16];
    int tid = threadIdx.x;
    int lane = tid & 63, wid = tid >> 6;
    const float* logits = params + 3072;
    float v0 = logits[tid], v1 = logits[tid + 1024], v2 = logits[tid + 2048], v3 = logits[tid + 3072];
    float m = fmaxf(fmaxf(v0, v1), fmaxf(v2, v3));
#pragma unroll
    for (int off = 32; off > 0; off >>= 1) m = fmaxf(m, __shfl_down(m, off));
    if (lane == 0) sm[wid] = m;
    __syncthreads();
    if (tid == 0) {
        float mm = sm[0];
        for (int i = 1; i < 16; ++i) mm = fmaxf(mm, sm[i]);
        sm[0] = mm;
    }
    __syncthreads();
    float mm = sm[0];
    float e0 = expf(v0 - mm), e1 = expf(v1 - mm), e2 = expf(v2 - mm), e3 = expf(v3 - mm);
    float s = e0 + e1 + e2 + e3;
#pragma unroll
    for (int off = 32; off > 0; off >>= 1) s += __shfl_down(s, off);
    __syncthreads();
    if (lane == 0) sm[wid] = s;
    __syncthreads();
    if (tid == 0) {
        float ss = 0.f;
        for (int i = 0; i < 16; ++i) ss += sm[i];
        sm[0] = ss;
    }
    __syncthreads();
    float gate = sigmoidf_(params[7168]);
    float scale = gate / sm[0];
    wv[tid] = e0 * scale; wv[tid + 1024] = e1 * scale;
    wv[tid + 2048] = e2 * scale; wv[tid + 3072] = e3 * scale;
    erase[tid] = sigmoidf_(params[1024 + tid]);
    addv[tid]  = tanhf(params[2048 + tid]);
}

// K10: memory update (block = slot) + out finalize on blocks 0-7. grid 4096x256.
__global__ void k10_memupd(const float* __restrict__ memory, const float* __restrict__ wv,
                           const float* __restrict__ erase, const float* __restrict__ addv,
                           const float* __restrict__ usage_new, float* __restrict__ newmem,
                           const float* __restrict__ outh, const float* __restrict__ outrv,
                           const float* __restrict__ out_b, float* __restrict__ out) {
    int s = blockIdx.x;
    int t = threadIdx.x;
    float w = wv[s];
    float mask = (usage_new[s] < 0.1f) ? 0.f : 1.f;
    float4 m = ((const float4*)memory)[(size_t)s * 256 + t];
    float4 e = ((const float4*)erase)[t];
    float4 a = ((const float4*)addv)[t];
    float4 r;
    r.x = mask * m.x * (1.f - w * e.x) + w * a.x;
    r.y = mask * m.y * (1.f - w * e.y) + w * a.y;
    r.z = mask * m.z * (1.f - w * e.z) + w * a.z;
    r.w = mask * m.w * (1.f - w * e.w) + w * a.w;
    ((float4*)newmem)[(size_t)s * 256 + t] = r;
    if (s < 8) {
        int i = s * 256 + t;
        out[i] = outh[i] + outrv[i] + out_b[i];
    }
}

extern "C" void kernel_launch(void* const* d_in, const int* in_sizes, int n_in,
                              void* d_out_, int out_size, void* d_ws, size_t ws_size,
                              hipStream_t stream) {
    const float* x      = (const float*)d_in[0];
    const float* h_prev = (const float*)d_in[1];
    const float* c_prev = (const float*)d_in[2];
    const float* memory = (const float*)d_in[3];
    const float* usage  = (const float*)d_in[4];
    const float* read_W = (const float*)d_in[5];
    const float* read_b = (const float*)d_in[6];
    const float* W_ih   = (const float*)d_in[7];
    const float* b_ih   = (const float*)d_in[8];
    const float* W_hh   = (const float*)d_in[9];
    const float* b_hh   = (const float*)d_in[10];
    const float* head_W = (const float*)d_in[11];
    const float* head_b = (const float*)d_in[12];
    const float* out_W  = (const float*)d_in[13];
    const float* out_b  = (const float*)d_in[14];

    float* d_out = (float*)d_out_;
    float* ws = (float*)d_ws;

    // workspace layout (floats)
    float* rk      = ws;            // 1024
    float* sim     = ws + 1024;     // 4096
    float* rw      = ws + 5120;     // 4096
    float* rv      = ws + 9216;     // 1024
    float* gx      = ws + 10240;    // 8192
    float* gh      = ws + 18432;    // 8192
    float* grv     = ws + 26624;    // 8192
    float* params  = ws + 34816;    // 7169 (pad to 42240)
    float* outh    = ws + 42240;    // 2048
    float* outrv   = ws + 44288;    // 2048
    float* wvv     = ws + 46336;    // 4096
    float* erase   = ws + 50432;    // 1024
    float* addv    = ws + 51456;    // 1024
    float* partial = ws + 52480;    // 64*1024

    // output layout: out | h_new | c_new | new_memory | usage_new
    float* out       = d_out;
    float* h_new     = d_out + 2048;
    float* c_new     = d_out + 4096;
    float* newmem    = d_out + 6144;
    float* usage_new = d_out + 6144 + (size_t)MEM_SLOTS * MEM_DIM;

    k1_rk_bg<<<1152, 256, 0, stream>>>(read_W, read_b, h_prev, W_hh, W_ih, x, rk, gh, gx);
    k2_sim_bg<<<2048, 256, 0, stream>>>(memory, rk, h_prev, W_hh, W_ih, x, sim, gh, gx);
    k3_smx_bg<<<513, 256, 0, stream>>>(sim, usage, rw, usage_new, h_prev, W_hh, W_ih, x, gh, gx);
    k4_rvp_bg<<<1216, 256, 0, stream>>>(memory, rw, partial, h_prev, W_hh, W_ih, x, gh, gx);
    k5_rvr_bg<<<513, 256, 0, stream>>>(partial, rv, h_prev, W_hh, W_ih, x, gh, gx);
    k6_grv_outrv<<<2560, 256, 0, stream>>>(W_ih, out_W, rv, grv, outrv);
    k7_lstm<<<8, 256, 0, stream>>>(gx, grv, gh, b_ih, b_hh, c_prev, c_new, h_new);
    k8_head_out<<<2049, 256, 0, stream>>>(head_W, head_b, out_W, h_new, params, outh);
    k9_smxw<<<1, 1024, 0, stream>>>(params, wvv, erase, addv);
    k10_memupd<<<4096, 256, 0, stream>>>(memory, wvv, erase, addv, usage_new, newmem,
                                         outh, outrv, out_b, out);
}

// Round 10
// 75.158 us; speedup vs baseline: 1.0035x; 1.0035x over previous
//
#include <hip/hip_runtime.h>
#include <math.h>

// ---------------------------------------------------------------------------
// PrefrontalCortex, batch=1, fp32 — R10 = R8 (proven 73.5us) + ONE change:
// out_rv rows moved from K8 (BW-heavy phase) into K6 (latency burst).
// R9's global rebalance regressed (75.4) -> reverted; only the isolated
// out_rv move is kept.
// Model: HBM-sourced reads cap ~3.15 TB/s chip-wide; L3-warm reads ~6.7 TB/s;
// writes ~7 TB/s. Structure overlaps the serial spine with bg weight
// streaming; kernel boundaries are the (cheap) device-wide barriers.
// bg units: u<8192 -> gh[u]=W_hh[u,:]*h_prev ; u>=8192 -> gx[u-8192]=
// W_ih[u-8192,0:2048]*x. Distribution (R8): K1[0,3072) K2[3072,7168)
// K3[7168,10240) K4[10240,13312) K5[13312,16384).
// ---------------------------------------------------------------------------

#define HIDDEN_DIM 2048
#define MEM_SLOTS 4096
#define MEM_DIM 1024

typedef float floatx4 __attribute__((ext_vector_type(4)));

static __device__ __forceinline__ float sigmoidf_(float x) {
    return 1.0f / (1.0f + expf(-x));
}

// wave-level dot, K4F4 float4 elems (256|512), valid on lane 0.
template<int K4F4>
static __device__ __forceinline__ float rowdot(const float4* __restrict__ Wr,
                                               const float4* __restrict__ v4,
                                               int lane) {
    float a0 = 0.f, a1 = 0.f, a2 = 0.f, a3 = 0.f;
#pragma unroll
    for (int i0 = 0; i0 < K4F4; i0 += 256) {
        int i = i0 + lane;
        floatx4 w0 = *(const floatx4*)(Wr + i);
        floatx4 w1 = *(const floatx4*)(Wr + i + 64);
        floatx4 w2 = *(const floatx4*)(Wr + i + 128);
        floatx4 w3 = *(const floatx4*)(Wr + i + 192);
        floatx4 x0 = *(const floatx4*)(v4 + i);
        floatx4 x1 = *(const floatx4*)(v4 + i + 64);
        floatx4 x2 = *(const floatx4*)(v4 + i + 128);
        floatx4 x3 = *(const floatx4*)(v4 + i + 192);
        a0 = fmaf(w0.x, x0.x, a0); a0 = fmaf(w0.y, x0.y, a0);
        a0 = fmaf(w0.z, x0.z, a0); a0 = fmaf(w0.w, x0.w, a0);
        a1 = fmaf(w1.x, x1.x, a1); a1 = fmaf(w1.y, x1.y, a1);
        a1 = fmaf(w1.z, x1.z, a1); a1 = fmaf(w1.w, x1.w, a1);
        a2 = fmaf(w2.x, x2.x, a2); a2 = fmaf(w2.y, x2.y, a2);
        a2 = fmaf(w2.z, x2.z, a2); a2 = fmaf(w2.w, x2.w, a2);
        a3 = fmaf(w3.x, x3.x, a3); a3 = fmaf(w3.y, x3.y, a3);
        a3 = fmaf(w3.z, x3.z, a3); a3 = fmaf(w3.w, x3.w, a3);
    }
    float acc = (a0 + a1) + (a2 + a3);
#pragma unroll
    for (int off = 32; off > 0; off >>= 1) acc += __shfl_down(acc, off);
    return acc;
}

static __device__ __forceinline__ void do_bg(int u, const float4* whh4,
                                             const float4* wih4, const float4* h4,
                                             const float4* x4, float* gh, float* gx,
                                             int lane) {
    if (u < 8192) {
        float d = rowdot<512>(whh4 + (size_t)u * 512, h4, lane);
        if (lane == 0) gh[u] = d;
    } else {
        int r = u - 8192;
        float d = rowdot<512>(wih4 + (size_t)r * 768, x4, lane);
        if (lane == 0) gx[r] = d;
    }
}

// K1: readkey (blocks 0-255) + bg [0,3072) (blocks 256-1023). grid 1024x256.
__global__ void k1_rk_bg(const float* __restrict__ read_W, const float* __restrict__ read_b,
                         const float* __restrict__ h_prev, const float* __restrict__ W_hh,
                         const float* __restrict__ W_ih, const float* __restrict__ x,
                         float* __restrict__ rk, float* __restrict__ gh, float* __restrict__ gx) {
    int lane = threadIdx.x & 63;
    int gw = blockIdx.x * 4 + (threadIdx.x >> 6);
    const float4* h4 = (const float4*)h_prev;
    if (gw < 1024) {
        float d = rowdot<512>((const float4*)read_W + (size_t)gw * 512, h4, lane);
        if (lane == 0) rk[gw] = tanhf(d + read_b[gw]);
    } else {
        do_bg(gw - 1024, (const float4*)W_hh, (const float4*)W_ih, h4,
              (const float4*)x, gh, gx, lane);
    }
}

// K2: sim (blocks 0-1023) + bg [3072,7168) (blocks 1024-2047). grid 2048x256.
__global__ void k2_sim_bg(const float* __restrict__ memory, const float* __restrict__ rk,
                          const float* __restrict__ h_prev, const float* __restrict__ W_hh,
                          const float* __restrict__ W_ih, const float* __restrict__ x,
                          float* __restrict__ sim, float* __restrict__ gh, float* __restrict__ gx) {
    int lane = threadIdx.x & 63;
    int gw = blockIdx.x * 4 + (threadIdx.x >> 6);
    if (gw < 4096) {
        float d = rowdot<256>((const float4*)memory + (size_t)gw * 256, (const float4*)rk, lane);
        if (lane == 0) sim[gw] = d;
    } else {
        do_bg(3072 + (gw - 4096), (const float4*)W_hh, (const float4*)W_ih,
              (const float4*)h_prev, (const float4*)x, gh, gx, lane);
    }
}

// K3: softmax_rw (block 0, 1024 thr) + bg [7168,10240). grid 193x1024.
__global__ void k3_smx_bg(const float* __restrict__ sim, const float* __restrict__ usage,
                          float* __restrict__ rw, float* __restrict__ usage_out,
                          const float* __restrict__ h_prev, const float* __restrict__ W_hh,
                          const float* __restrict__ W_ih, const float* __restrict__ x,
                          float* __restrict__ gh, float* __restrict__ gx) {
    int tid = threadIdx.x;
    int lane = tid & 63, wid = tid >> 6;
    if (blockIdx.x != 0) {
        int u = 7168 + (blockIdx.x - 1) * 16 + wid;
        do_bg(u, (const float4*)W_hh, (const float4*)W_ih, (const float4*)h_prev,
              (const float4*)x, gh, gx, lane);
        return;
    }
    __shared__ float sm[16];
    float v0 = sim[tid], v1 = sim[tid + 1024], v2 = sim[tid + 2048], v3 = sim[tid + 3072];
    float m = fmaxf(fmaxf(v0, v1), fmaxf(v2, v3));
#pragma unroll
    for (int off = 32; off > 0; off >>= 1) m = fmaxf(m, __shfl_down(m, off));
    if (lane == 0) sm[wid] = m;
    __syncthreads();
    if (tid == 0) {
        float mm = sm[0];
        for (int i = 1; i < 16; ++i) mm = fmaxf(mm, sm[i]);
        sm[0] = mm;
    }
    __syncthreads();
    float mm = sm[0];
    float e0 = expf(v0 - mm), e1 = expf(v1 - mm), e2 = expf(v2 - mm), e3 = expf(v3 - mm);
    float s = e0 + e1 + e2 + e3;
#pragma unroll
    for (int off = 32; off > 0; off >>= 1) s += __shfl_down(s, off);
    __syncthreads();
    if (lane == 0) sm[wid] = s;
    __syncthreads();
    if (tid == 0) {
        float ss = 0.f;
        for (int i = 0; i < 16; ++i) ss += sm[i];
        sm[0] = ss;
    }
    __syncthreads();
    float inv = 1.f / sm[0];
    float r0 = e0 * inv, r1 = e1 * inv, r2 = e2 * inv, r3 = e3 * inv;
    rw[tid] = r0; rw[tid + 1024] = r1; rw[tid + 2048] = r2; rw[tid + 3072] = r3;
    usage_out[tid]        = usage[tid]        + r0;
    usage_out[tid + 1024] = usage[tid + 1024] + r1;
    usage_out[tid + 2048] = usage[tid + 2048] + r2;
    usage_out[tid + 3072] = usage[tid + 3072] + r3;
}

// K4: rv-partial (blocks 0-63) + bg [10240,13312) (blocks 64-831). grid 832x256.
__global__ void k4_rvp_bg(const float* __restrict__ memory, const float* __restrict__ rw,
                          float* __restrict__ partial,
                          const float* __restrict__ h_prev, const float* __restrict__ W_hh,
                          const float* __restrict__ W_ih, const float* __restrict__ x,
                          float* __restrict__ gh, float* __restrict__ gx) {
    int t = threadIdx.x;
    int lane = t & 63;
    if (blockIdx.x >= 64) {
        int u = 10240 + (blockIdx.x - 64) * 4 + (t >> 6);
        do_bg(u, (const float4*)W_hh, (const float4*)W_ih, (const float4*)h_prev,
              (const float4*)x, gh, gx, lane);
        return;
    }
    int chunk = blockIdx.x;
    const float4* mem4 = (const float4*)memory;
    float4 acc = make_float4(0.f, 0.f, 0.f, 0.f);
    int s0 = chunk * 64;
    for (int s = s0; s < s0 + 64; ++s) {
        float w = rw[s];
        float4 m = mem4[(size_t)s * 256 + t];
        acc.x = fmaf(w, m.x, acc.x);
        acc.y = fmaf(w, m.y, acc.y);
        acc.z = fmaf(w, m.z, acc.z);
        acc.w = fmaf(w, m.w, acc.w);
    }
    ((float4*)partial)[chunk * 256 + t] = acc;
}

// K5: rv-reduce (block 0, 1024 thr) + bg [13312,16384). grid 193x1024.
__global__ void k5_rvr_bg(const float* __restrict__ partial, float* __restrict__ rv,
                          const float* __restrict__ h_prev, const float* __restrict__ W_hh,
                          const float* __restrict__ W_ih, const float* __restrict__ x,
                          float* __restrict__ gh, float* __restrict__ gx) {
    int tid = threadIdx.x;
    int lane = tid & 63, wid = tid >> 6;
    if (blockIdx.x != 0) {
        int u = 13312 + (blockIdx.x - 1) * 16 + wid;
        do_bg(u, (const float4*)W_hh, (const float4*)W_ih, (const float4*)h_prev,
              (const float4*)x, gh, gx, lane);
        return;
    }
    float s = 0.f;
    for (int k = 0; k < 64; ++k) s += partial[k * 1024 + tid];
    rv[tid] = s;
}

// K6: grv (waves 0-8191) + out_rv (waves 8192-10239). grid 2560x256.
__global__ void k6_grv_outrv(const float* __restrict__ W_ih, const float* __restrict__ out_W,
                             const float* __restrict__ rv, float* __restrict__ grv,
                             float* __restrict__ outrv) {
    int lane = threadIdx.x & 63;
    int gw = blockIdx.x * 4 + (threadIdx.x >> 6);
    const float4* rv4 = (const float4*)rv;
    if (gw < 8192) {
        float d = rowdot<256>((const float4*)W_ih + (size_t)gw * 768 + 512, rv4, lane);
        if (lane == 0) grv[gw] = d;
    } else {
        int o = gw - 8192;
        float d = rowdot<256>((const float4*)out_W + (size_t)o * 768 + 512, rv4, lane);
        if (lane == 0) outrv[o] = d;
    }
}

// K7: LSTM elementwise. grid 8x256.
__global__ void k7_lstm(const float* __restrict__ gx, const float* __restrict__ grv,
                        const float* __restrict__ gh, const float* __restrict__ b_ih,
                        const float* __restrict__ b_hh, const float* __restrict__ c_prev,
                        float* __restrict__ c_new, float* __restrict__ h_new) {
    int t = blockIdx.x * 256 + threadIdx.x;
    float gi = gx[t]        + grv[t]        + gh[t]        + b_ih[t]        + b_hh[t];
    float gf = gx[2048 + t] + grv[2048 + t] + gh[2048 + t] + b_ih[2048 + t] + b_hh[2048 + t];
    float gg = gx[4096 + t] + grv[4096 + t] + gh[4096 + t] + b_ih[4096 + t] + b_hh[4096 + t];
    float go = gx[6144 + t] + grv[6144 + t] + gh[6144 + t] + b_ih[6144 + t] + b_hh[6144 + t];
    float c = sigmoidf_(gf) * c_prev[t] + sigmoidf_(gi) * tanhf(gg);
    float h = sigmoidf_(go) * tanhf(c);
    c_new[t] = c;
    h_new[t] = h;
}

// K8: head rows 1024..7168 (u<6145) + out_h (u<8193). grid 2049x256.
__global__ void k8_head_out(const float* __restrict__ head_W, const float* __restrict__ head_b,
                            const float* __restrict__ out_W, const float* __restrict__ h_new,
                            float* __restrict__ params, float* __restrict__ outh) {
    int lane = threadIdx.x & 63;
    int u = blockIdx.x * 4 + (threadIdx.x >> 6);
    const float4* hn4 = (const float4*)h_new;
    if (u < 6145) {
        int r = 1024 + u;
        float d = rowdot<512>((const float4*)head_W + (size_t)r * 512, hn4, lane);
        if (lane == 0) params[r] = d + head_b[r];
    } else if (u < 8193) {
        int o = u - 6145;
        float d = rowdot<512>((const float4*)out_W + (size_t)o * 768, hn4, lane);
        if (lane == 0) outh[o] = d;
    }
}

// K9: softmax_w. grid 1x1024.
__global__ void k9_smxw(const float* __restrict__ params, float* __restrict__ wv,
                        float* __restrict__ erase, float* __restrict__ addv) {
    __shared__ float sm[16];
    int tid = threadIdx.x;
    int lane = tid & 63, wid = tid >> 6;
    const float* logits = params + 3072;
    float v0 = logits[tid], v1 = logits[tid + 1024], v2 = logits[tid + 2048], v3 = logits[tid + 3072];
    float m = fmaxf(fmaxf(v0, v1), fmaxf(v2, v3));
#pragma unroll
    for (int off = 32; off > 0; off >>= 1) m = fmaxf(m, __shfl_down(m, off));
    if (lane == 0) sm[wid] = m;
    __syncthreads();
    if (tid == 0) {
        float mm = sm[0];
        for (int i = 1; i < 16; ++i) mm = fmaxf(mm, sm[i]);
        sm[0] = mm;
    }
    __syncthreads();
    float mm = sm[0];
    float e0 = expf(v0 - mm), e1 = expf(v1 - mm), e2 = expf(v2 - mm), e3 = expf(v3 - mm);
    float s = e0 + e1 + e2 + e3;
#pragma unroll
    for (int off = 32; off > 0; off >>= 1) s += __shfl_down(s, off);
    __syncthreads();
    if (lane == 0) sm[wid] = s;
    __syncthreads();
    if (tid == 0) {
        float ss = 0.f;
        for (int i = 0; i < 16; ++i) ss += sm[i];
        sm[0] = ss;
    }
    __syncthreads();
    float gate = sigmoidf_(params[7168]);
    float scale = gate / sm[0];
    wv[tid] = e0 * scale; wv[tid + 1024] = e1 * scale;
    wv[tid + 2048] = e2 * scale; wv[tid + 3072] = e3 * scale;
    erase[tid] = sigmoidf_(params[1024 + tid]);
    addv[tid]  = tanhf(params[2048 + tid]);
}

// K10: memory update (block = slot) + out finalize on blocks 0-7. grid 4096x256.
__global__ void k10_memupd(const float* __restrict__ memory, const float* __restrict__ wv,
                           const float* __restrict__ erase, const float* __restrict__ addv,
                           const float* __restrict__ usage_new, float* __restrict__ newmem,
                           const float* __restrict__ outh, const float* __restrict__ outrv,
                           const float* __restrict__ out_b, float* __restrict__ out) {
    int s = blockIdx.x;
    int t = threadIdx.x;
    float w = wv[s];
    float mask = (usage_new[s] < 0.1f) ? 0.f : 1.f;
    float4 m = ((const float4*)memory)[(size_t)s * 256 + t];
    float4 e = ((const float4*)erase)[t];
    float4 a = ((const float4*)addv)[t];
    float4 r;
    r.x = mask * m.x * (1.f - w * e.x) + w * a.x;
    r.y = mask * m.y * (1.f - w * e.y) + w * a.y;
    r.z = mask * m.z * (1.f - w * e.z) + w * a.z;
    r.w = mask * m.w * (1.f - w * e.w) + w * a.w;
    ((float4*)newmem)[(size_t)s * 256 + t] = r;
    if (s < 8) {
        int i = s * 256 + t;
        out[i] = outh[i] + outrv[i] + out_b[i];
    }
}

extern "C" void kernel_launch(void* const* d_in, const int* in_sizes, int n_in,
                              void* d_out_, int out_size, void* d_ws, size_t ws_size,
                              hipStream_t stream) {
    const float* x      = (const float*)d_in[0];
    const float* h_prev = (const float*)d_in[1];
    const float* c_prev = (const float*)d_in[2];
    const float* memory = (const float*)d_in[3];
    const float* usage  = (const float*)d_in[4];
    const float* read_W = (const float*)d_in[5];
    const float* read_b = (const float*)d_in[6];
    const float* W_ih   = (const float*)d_in[7];
    const float* b_ih   = (const float*)d_in[8];
    const float* W_hh   = (const float*)d_in[9];
    const float* b_hh   = (const float*)d_in[10];
    const float* head_W = (const float*)d_in[11];
    const float* head_b = (const float*)d_in[12];
    const float* out_W  = (const float*)d_in[13];
    const float* out_b  = (const float*)d_in[14];

    float* d_out = (float*)d_out_;
    float* ws = (float*)d_ws;

    // workspace layout (floats)
    float* rk      = ws;            // 1024
    float* sim     = ws + 1024;     // 4096
    float* rw      = ws + 5120;     // 4096
    float* rv      = ws + 9216;     // 1024
    float* gx      = ws + 10240;    // 8192
    float* gh      = ws + 18432;    // 8192
    float* grv     = ws + 26624;    // 8192
    float* params  = ws + 34816;    // 7169 (pad to 42240)
    float* outh    = ws + 42240;    // 2048
    float* outrv   = ws + 44288;    // 2048
    float* wvv     = ws + 46336;    // 4096
    float* erase   = ws + 50432;    // 1024
    float* addv    = ws + 51456;    // 1024
    float* partial = ws + 52480;    // 64*1024

    // output layout: out | h_new | c_new | new_memory | usage_new
    float* out       = d_out;
    float* h_new     = d_out + 2048;
    float* c_new     = d_out + 4096;
    float* newmem    = d_out + 6144;
    float* usage_new = d_out + 6144 + (size_t)MEM_SLOTS * MEM_DIM;

    k1_rk_bg<<<1024, 256, 0, stream>>>(read_W, read_b, h_prev, W_hh, W_ih, x, rk, gh, gx);
    k2_sim_bg<<<2048, 256, 0, stream>>>(memory, rk, h_prev, W_hh, W_ih, x, sim, gh, gx);
    k3_smx_bg<<<193, 1024, 0, stream>>>(sim, usage, rw, usage_new, h_prev, W_hh, W_ih, x, gh, gx);
    k4_rvp_bg<<<832, 256, 0, stream>>>(memory, rw, partial, h_prev, W_hh, W_ih, x, gh, gx);
    k5_rvr_bg<<<193, 1024, 0, stream>>>(partial, rv, h_prev, W_hh, W_ih, x, gh, gx);
    k6_grv_outrv<<<2560, 256, 0, stream>>>(W_ih, out_W, rv, grv, outrv);
    k7_lstm<<<8, 256, 0, stream>>>(gx, grv, gh, b_ih, b_hh, c_prev, c_new, h_new);
    k8_head_out<<<2049, 256, 0, stream>>>(head_W, head_b, out_W, h_new, params, outh);
    k9_smxw<<<1, 1024, 0, stream>>>(params, wvv, erase, addv);
    k10_memupd<<<4096, 256, 0, stream>>>(memory, wvv, erase, addv, usage_new, newmem,
                                         outh, outrv, out_b, out);
}

// Round 11
// 74.142 us; speedup vs baseline: 1.0172x; 1.0137x over previous
//
#include <hip/hip_runtime.h>
#include <math.h>

// ---------------------------------------------------------------------------
// PrefrontalCortex, batch=1, fp32 — R11 = exact restore of R8 (best: 73.5us).
// R9 (rebalance, 75.4) and R10 (out_rv->K6, 75.2) both regressed; R8 is the
// local optimum of the spine/stream-overlap structure.
// Model (R1-R10 evidence): cold HBM reads cap ~3.15 TB/s chip-wide, L3-warm
// reads ~6.7 TB/s, writes ~7 TB/s posted. ~298 MB blended reads -> ~70us
// floor; R8 sits within ~5% of it. Kernel boundaries = cheap device barrier
// (~1-2us); coop grid.sync = ~60us on 8 XCDs (R7) - never again.
// bg units: u<8192 -> gh[u]=W_hh[u,:]*h_prev ; u>=8192 -> gx[u-8192]=
// W_ih[u-8192,0:2048]*x. Distribution: K1[0,3072) K2[3072,7168)
// K3[7168,10240) K4[10240,13312) K5[13312,16384).
// ---------------------------------------------------------------------------

#define HIDDEN_DIM 2048
#define MEM_SLOTS 4096
#define MEM_DIM 1024

typedef float floatx4 __attribute__((ext_vector_type(4)));

static __device__ __forceinline__ float sigmoidf_(float x) {
    return 1.0f / (1.0f + expf(-x));
}

// wave-level dot, K4F4 float4 elems (256|512), valid on lane 0.
template<int K4F4>
static __device__ __forceinline__ float rowdot(const float4* __restrict__ Wr,
                                               const float4* __restrict__ v4,
                                               int lane) {
    float a0 = 0.f, a1 = 0.f, a2 = 0.f, a3 = 0.f;
#pragma unroll
    for (int i0 = 0; i0 < K4F4; i0 += 256) {
        int i = i0 + lane;
        floatx4 w0 = *(const floatx4*)(Wr + i);
        floatx4 w1 = *(const floatx4*)(Wr + i + 64);
        floatx4 w2 = *(const floatx4*)(Wr + i + 128);
        floatx4 w3 = *(const floatx4*)(Wr + i + 192);
        floatx4 x0 = *(const floatx4*)(v4 + i);
        floatx4 x1 = *(const floatx4*)(v4 + i + 64);
        floatx4 x2 = *(const floatx4*)(v4 + i + 128);
        floatx4 x3 = *(const floatx4*)(v4 + i + 192);
        a0 = fmaf(w0.x, x0.x, a0); a0 = fmaf(w0.y, x0.y, a0);
        a0 = fmaf(w0.z, x0.z, a0); a0 = fmaf(w0.w, x0.w, a0);
        a1 = fmaf(w1.x, x1.x, a1); a1 = fmaf(w1.y, x1.y, a1);
        a1 = fmaf(w1.z, x1.z, a1); a1 = fmaf(w1.w, x1.w, a1);
        a2 = fmaf(w2.x, x2.x, a2); a2 = fmaf(w2.y, x2.y, a2);
        a2 = fmaf(w2.z, x2.z, a2); a2 = fmaf(w2.w, x2.w, a2);
        a3 = fmaf(w3.x, x3.x, a3); a3 = fmaf(w3.y, x3.y, a3);
        a3 = fmaf(w3.z, x3.z, a3); a3 = fmaf(w3.w, x3.w, a3);
    }
    float acc = (a0 + a1) + (a2 + a3);
#pragma unroll
    for (int off = 32; off > 0; off >>= 1) acc += __shfl_down(acc, off);
    return acc;
}

static __device__ __forceinline__ void do_bg(int u, const float4* whh4,
                                             const float4* wih4, const float4* h4,
                                             const float4* x4, float* gh, float* gx,
                                             int lane) {
    if (u < 8192) {
        float d = rowdot<512>(whh4 + (size_t)u * 512, h4, lane);
        if (lane == 0) gh[u] = d;
    } else {
        int r = u - 8192;
        float d = rowdot<512>(wih4 + (size_t)r * 768, x4, lane);
        if (lane == 0) gx[r] = d;
    }
}

// K1: readkey (blocks 0-255) + bg [0,3072) (blocks 256-1023). grid 1024x256.
__global__ void k1_rk_bg(const float* __restrict__ read_W, const float* __restrict__ read_b,
                         const float* __restrict__ h_prev, const float* __restrict__ W_hh,
                         const float* __restrict__ W_ih, const float* __restrict__ x,
                         float* __restrict__ rk, float* __restrict__ gh, float* __restrict__ gx) {
    int lane = threadIdx.x & 63;
    int gw = blockIdx.x * 4 + (threadIdx.x >> 6);
    const float4* h4 = (const float4*)h_prev;
    if (gw < 1024) {
        float d = rowdot<512>((const float4*)read_W + (size_t)gw * 512, h4, lane);
        if (lane == 0) rk[gw] = tanhf(d + read_b[gw]);
    } else {
        do_bg(gw - 1024, (const float4*)W_hh, (const float4*)W_ih, h4,
              (const float4*)x, gh, gx, lane);
    }
}

// K2: sim (blocks 0-1023) + bg [3072,7168) (blocks 1024-2047). grid 2048x256.
__global__ void k2_sim_bg(const float* __restrict__ memory, const float* __restrict__ rk,
                          const float* __restrict__ h_prev, const float* __restrict__ W_hh,
                          const float* __restrict__ W_ih, const float* __restrict__ x,
                          float* __restrict__ sim, float* __restrict__ gh, float* __restrict__ gx) {
    int lane = threadIdx.x & 63;
    int gw = blockIdx.x * 4 + (threadIdx.x >> 6);
    if (gw < 4096) {
        float d = rowdot<256>((const float4*)memory + (size_t)gw * 256, (const float4*)rk, lane);
        if (lane == 0) sim[gw] = d;
    } else {
        do_bg(3072 + (gw - 4096), (const float4*)W_hh, (const float4*)W_ih,
              (const float4*)h_prev, (const float4*)x, gh, gx, lane);
    }
}

// K3: softmax_rw (block 0, 1024 thr) + bg [7168,10240). grid 193x1024.
__global__ void k3_smx_bg(const float* __restrict__ sim, const float* __restrict__ usage,
                          float* __restrict__ rw, float* __restrict__ usage_out,
                          const float* __restrict__ h_prev, const float* __restrict__ W_hh,
                          const float* __restrict__ W_ih, const float* __restrict__ x,
                          float* __restrict__ gh, float* __restrict__ gx) {
    int tid = threadIdx.x;
    int lane = tid & 63, wid = tid >> 6;
    if (blockIdx.x != 0) {
        int u = 7168 + (blockIdx.x - 1) * 16 + wid;
        do_bg(u, (const float4*)W_hh, (const float4*)W_ih, (const float4*)h_prev,
              (const float4*)x, gh, gx, lane);
        return;
    }
    __shared__ float sm[16];
    float v0 = sim[tid], v1 = sim[tid + 1024], v2 = sim[tid + 2048], v3 = sim[tid + 3072];
    float m = fmaxf(fmaxf(v0, v1), fmaxf(v2, v3));
#pragma unroll
    for (int off = 32; off > 0; off >>= 1) m = fmaxf(m, __shfl_down(m, off));
    if (lane == 0) sm[wid] = m;
    __syncthreads();
    if (tid == 0) {
        float mm = sm[0];
        for (int i = 1; i < 16; ++i) mm = fmaxf(mm, sm[i]);
        sm[0] = mm;
    }
    __syncthreads();
    float mm = sm[0];
    float e0 = expf(v0 - mm), e1 = expf(v1 - mm), e2 = expf(v2 - mm), e3 = expf(v3 - mm);
    float s = e0 + e1 + e2 + e3;
#pragma unroll
    for (int off = 32; off > 0; off >>= 1) s += __shfl_down(s, off);
    __syncthreads();
    if (lane == 0) sm[wid] = s;
    __syncthreads();
    if (tid == 0) {
        float ss = 0.f;
        for (int i = 0; i < 16; ++i) ss += sm[i];
        sm[0] = ss;
    }
    __syncthreads();
    float inv = 1.f / sm[0];
    float r0 = e0 * inv, r1 = e1 * inv, r2 = e2 * inv, r3 = e3 * inv;
    rw[tid] = r0; rw[tid + 1024] = r1; rw[tid + 2048] = r2; rw[tid + 3072] = r3;
    usage_out[tid]        = usage[tid]        + r0;
    usage_out[tid + 1024] = usage[tid + 1024] + r1;
    usage_out[tid + 2048] = usage[tid + 2048] + r2;
    usage_out[tid + 3072] = usage[tid + 3072] + r3;
}

// K4: rv-partial (blocks 0-63) + bg [10240,13312) (blocks 64-831). grid 832x256.
__global__ void k4_rvp_bg(const float* __restrict__ memory, const float* __restrict__ rw,
                          float* __restrict__ partial,
                          const float* __restrict__ h_prev, const float* __restrict__ W_hh,
                          const float* __restrict__ W_ih, const float* __restrict__ x,
                          float* __restrict__ gh, float* __restrict__ gx) {
    int t = threadIdx.x;
    int lane = t & 63;
    if (blockIdx.x >= 64) {
        int u = 10240 + (blockIdx.x - 64) * 4 + (t >> 6);
        do_bg(u, (const float4*)W_hh, (const float4*)W_ih, (const float4*)h_prev,
              (const float4*)x, gh, gx, lane);
        return;
    }
    int chunk = blockIdx.x;
    const float4* mem4 = (const float4*)memory;
    float4 acc = make_float4(0.f, 0.f, 0.f, 0.f);
    int s0 = chunk * 64;
    for (int s = s0; s < s0 + 64; ++s) {
        float w = rw[s];
        float4 m = mem4[(size_t)s * 256 + t];
        acc.x = fmaf(w, m.x, acc.x);
        acc.y = fmaf(w, m.y, acc.y);
        acc.z = fmaf(w, m.z, acc.z);
        acc.w = fmaf(w, m.w, acc.w);
    }
    ((float4*)partial)[chunk * 256 + t] = acc;
}

// K5: rv-reduce (block 0, 1024 thr) + bg [13312,16384). grid 193x1024.
__global__ void k5_rvr_bg(const float* __restrict__ partial, float* __restrict__ rv,
                          const float* __restrict__ h_prev, const float* __restrict__ W_hh,
                          const float* __restrict__ W_ih, const float* __restrict__ x,
                          float* __restrict__ gh, float* __restrict__ gx) {
    int tid = threadIdx.x;
    int lane = tid & 63, wid = tid >> 6;
    if (blockIdx.x != 0) {
        int u = 13312 + (blockIdx.x - 1) * 16 + wid;
        do_bg(u, (const float4*)W_hh, (const float4*)W_ih, (const float4*)h_prev,
              (const float4*)x, gh, gx, lane);
        return;
    }
    float s = 0.f;
    for (int k = 0; k < 64; ++k) s += partial[k * 1024 + tid];
    rv[tid] = s;
}

// K6: grv[u] = W_ih[u, 2048:3072] . rv, 8192 rows. grid 2048x256.
__global__ void k6_grv(const float* __restrict__ W_ih, const float* __restrict__ rv,
                       float* __restrict__ grv) {
    int lane = threadIdx.x & 63;
    int gw = blockIdx.x * 4 + (threadIdx.x >> 6);
    float d = rowdot<256>((const float4*)W_ih + (size_t)gw * 768 + 512, (const float4*)rv, lane);
    if (lane == 0) grv[gw] = d;
}

// K7: LSTM elementwise. grid 8x256.
__global__ void k7_lstm(const float* __restrict__ gx, const float* __restrict__ grv,
                        const float* __restrict__ gh, const float* __restrict__ b_ih,
                        const float* __restrict__ b_hh, const float* __restrict__ c_prev,
                        float* __restrict__ c_new, float* __restrict__ h_new) {
    int t = blockIdx.x * 256 + threadIdx.x;
    float gi = gx[t]        + grv[t]        + gh[t]        + b_ih[t]        + b_hh[t];
    float gf = gx[2048 + t] + grv[2048 + t] + gh[2048 + t] + b_ih[2048 + t] + b_hh[2048 + t];
    float gg = gx[4096 + t] + grv[4096 + t] + gh[4096 + t] + b_ih[4096 + t] + b_hh[4096 + t];
    float go = gx[6144 + t] + grv[6144 + t] + gh[6144 + t] + b_ih[6144 + t] + b_hh[6144 + t];
    float c = sigmoidf_(gf) * c_prev[t] + sigmoidf_(gi) * tanhf(gg);
    float h = sigmoidf_(go) * tanhf(c);
    c_new[t] = c;
    h_new[t] = h;
}

// K8: head rows 1024..7168 (u<6145) + out_h (u<8193) + out_rv (u<10241).
// grid 2561x256.
__global__ void k8_head_out(const float* __restrict__ head_W, const float* __restrict__ head_b,
                            const float* __restrict__ out_W, const float* __restrict__ h_new,
                            const float* __restrict__ rv, float* __restrict__ params,
                            float* __restrict__ outh, float* __restrict__ outrv) {
    int lane = threadIdx.x & 63;
    int u = blockIdx.x * 4 + (threadIdx.x >> 6);
    const float4* hn4 = (const float4*)h_new;
    if (u < 6145) {
        int r = 1024 + u;
        float d = rowdot<512>((const float4*)head_W + (size_t)r * 512, hn4, lane);
        if (lane == 0) params[r] = d + head_b[r];
    } else if (u < 8193) {
        int o = u - 6145;
        float d = rowdot<512>((const float4*)out_W + (size_t)o * 768, hn4, lane);
        if (lane == 0) outh[o] = d;
    } else if (u < 10241) {
        int o = u - 8193;
        float d = rowdot<256>((const float4*)out_W + (size_t)o * 768 + 512, (const float4*)rv, lane);
        if (lane == 0) outrv[o] = d;
    }
}

// K9: softmax_w. grid 1x1024.
__global__ void k9_smxw(const float* __restrict__ params, float* __restrict__ wv,
                        float* __restrict__ erase, float* __restrict__ addv) {
    __shared__ float sm[16];
    int tid = threadIdx.x;
    int lane = tid & 63, wid = tid >> 6;
    const float* logits = params + 3072;
    float v0 = logits[tid], v1 = logits[tid + 1024], v2 = logits[tid + 2048], v3 = logits[tid + 3072];
    float m = fmaxf(fmaxf(v0, v1), fmaxf(v2, v3));
#pragma unroll
    for (int off = 32; off > 0; off >>= 1) m = fmaxf(m, __shfl_down(m, off));
    if (lane == 0) sm[wid] = m;
    __syncthreads();
    if (tid == 0) {
        float mm = sm[0];
        for (int i = 1; i < 16; ++i) mm = fmaxf(mm, sm[i]);
        sm[0] = mm;
    }
    __syncthreads();
    float mm = sm[0];
    float e0 = expf(v0 - mm), e1 = expf(v1 - mm), e2 = expf(v2 - mm), e3 = expf(v3 - mm);
    float s = e0 + e1 + e2 + e3;
#pragma unroll
    for (int off = 32; off > 0; off >>= 1) s += __shfl_down(s, off);
    __syncthreads();
    if (lane == 0) sm[wid] = s;
    __syncthreads();
    if (tid == 0) {
        float ss = 0.f;
        for (int i = 0; i < 16; ++i) ss += sm[i];
        sm[0] = ss;
    }
    __syncthreads();
    float gate = sigmoidf_(params[7168]);
    float scale = gate / sm[0];
    wv[tid] = e0 * scale; wv[tid + 1024] = e1 * scale;
    wv[tid + 2048] = e2 * scale; wv[tid + 3072] = e3 * scale;
    erase[tid] = sigmoidf_(params[1024 + tid]);
    addv[tid]  = tanhf(params[2048 + tid]);
}

// K10: memory update (block = slot) + out finalize on blocks 0-7. grid 4096x256.
__global__ void k10_memupd(const float* __restrict__ memory, const float* __restrict__ wv,
                           const float* __restrict__ erase, const float* __restrict__ addv,
                           const float* __restrict__ usage_new, float* __restrict__ newmem,
                           const float* __restrict__ outh, const float* __restrict__ outrv,
                           const float* __restrict__ out_b, float* __restrict__ out) {
    int s = blockIdx.x;
    int t = threadIdx.x;
    float w = wv[s];
    float mask = (usage_new[s] < 0.1f) ? 0.f : 1.f;
    float4 m = ((const float4*)memory)[(size_t)s * 256 + t];
    float4 e = ((const float4*)erase)[t];
    float4 a = ((const float4*)addv)[t];
    float4 r;
    r.x = mask * m.x * (1.f - w * e.x) + w * a.x;
    r.y = mask * m.y * (1.f - w * e.y) + w * a.y;
    r.z = mask * m.z * (1.f - w * e.z) + w * a.z;
    r.w = mask * m.w * (1.f - w * e.w) + w * a.w;
    ((float4*)newmem)[(size_t)s * 256 + t] = r;
    if (s < 8) {
        int i = s * 256 + t;
        out[i] = outh[i] + outrv[i] + out_b[i];
    }
}

extern "C" void kernel_launch(void* const* d_in, const int* in_sizes, int n_in,
                              void* d_out_, int out_size, void* d_ws, size_t ws_size,
                              hipStream_t stream) {
    const float* x      = (const float*)d_in[0];
    const float* h_prev = (const float*)d_in[1];
    const float* c_prev = (const float*)d_in[2];
    const float* memory = (const float*)d_in[3];
    const float* usage  = (const float*)d_in[4];
    const float* read_W = (const float*)d_in[5];
    const float* read_b = (const float*)d_in[6];
    const float* W_ih   = (const float*)d_in[7];
    const float* b_ih   = (const float*)d_in[8];
    const float* W_hh   = (const float*)d_in[9];
    const float* b_hh   = (const float*)d_in[10];
    const float* head_W = (const float*)d_in[11];
    const float* head_b = (const float*)d_in[12];
    const float* out_W  = (const float*)d_in[13];
    const float* out_b  = (const float*)d_in[14];

    float* d_out = (float*)d_out_;
    float* ws = (float*)d_ws;

    // workspace layout (floats)
    float* rk      = ws;            // 1024
    float* sim     = ws + 1024;     // 4096
    float* rw      = ws + 5120;     // 4096
    float* rv      = ws + 9216;     // 1024
    float* gx      = ws + 10240;    // 8192
    float* gh      = ws + 18432;    // 8192
    float* grv     = ws + 26624;    // 8192
    float* params  = ws + 34816;    // 7169 (pad to 42240)
    float* outh    = ws + 42240;    // 2048
    float* outrv   = ws + 44288;    // 2048
    float* wvv     = ws + 46336;    // 4096
    float* erase   = ws + 50432;    // 1024
    float* addv    = ws + 51456;    // 1024
    float* partial = ws + 52480;    // 64*1024

    // output layout: out | h_new | c_new | new_memory | usage_new
    float* out       = d_out;
    float* h_new     = d_out + 2048;
    float* c_new     = d_out + 4096;
    float* newmem    = d_out + 6144;
    float* usage_new = d_out + 6144 + (size_t)MEM_SLOTS * MEM_DIM;

    k1_rk_bg<<<1024, 256, 0, stream>>>(read_W, read_b, h_prev, W_hh, W_ih, x, rk, gh, gx);
    k2_sim_bg<<<2048, 256, 0, stream>>>(memory, rk, h_prev, W_hh, W_ih, x, sim, gh, gx);
    k3_smx_bg<<<193, 1024, 0, stream>>>(sim, usage, rw, usage_new, h_prev, W_hh, W_ih, x, gh, gx);
    k4_rvp_bg<<<832, 256, 0, stream>>>(memory, rw, partial, h_prev, W_hh, W_ih, x, gh, gx);
    k5_rvr_bg<<<193, 1024, 0, stream>>>(partial, rv, h_prev, W_hh, W_ih, x, gh, gx);
    k6_grv<<<2048, 256, 0, stream>>>(W_ih, rv, grv);
    k7_lstm<<<8, 256, 0, stream>>>(gx, grv, gh, b_ih, b_hh, c_prev, c_new, h_new);
    k8_head_out<<<2561, 256, 0, stream>>>(head_W, head_b, out_W, h_new, rv, params, outh, outrv);
    k9_smxw<<<1, 1024, 0, stream>>>(params, wvv, erase, addv);
    k10_memupd<<<4096, 256, 0, stream>>>(memory, wvv, erase, addv, usage_new, newmem,
                                         outh, outrv, out_b, out);
}